// Round 6
// baseline (49.687 us; speedup 1.0000x reference)
//
#include <hip/hip_runtime.h>

typedef __bf16 bf16x8 __attribute__((ext_vector_type(8)));
typedef float f32x4 __attribute__((ext_vector_type(4)));

__device__ __forceinline__ unsigned short f2bf(float f) {
  __bf16 h = (__bf16)f;
  return __builtin_bit_cast(unsigned short, h);
}

// d_ws layout: [0, 24576) bytes: wsB bf16 fragment-ordered (12288 shorts)
//              [24576, 24832): bias (64 floats)
// wsB flat idx = (((di*4 + jblk)*2 + kstep)*64 + lane)*8 + i
//   c   = kstep*32 + 4*(lane>>4) + (i&3) + 16*(i>>2)
//   fch = jblk*16 + (lane&15)
__global__ __launch_bounds__(256) void prep_kernel(
    const float* __restrict__ conv_w, const float* __restrict__ gamma,
    const float* __restrict__ beta, const float* __restrict__ mean,
    const float* __restrict__ var, unsigned short* __restrict__ wsB,
    float* __restrict__ bias) {
  int idx = blockIdx.x * 256 + threadIdx.x;
  if (idx >= 12288) return;
  int di    = idx >> 12;
  int r     = idx & 4095;
  int jblk  = r >> 10;
  int r2    = r & 1023;
  int kstep = r2 >> 9;
  int r3    = r2 & 511;
  int lane  = r3 >> 3;
  int i     = r3 & 7;
  int c   = kstep * 32 + 4 * (lane >> 4) + (i & 3) + 16 * (i >> 2);
  int fch = jblk * 16 + (lane & 15);
  float s = gamma[fch] * rsqrtf(var[fch] + 1e-3f);
  float v = conv_w[((di * 3 + 0) * 64 + c) * 64 + fch]
          + conv_w[((di * 3 + 1) * 64 + c) * 64 + fch]
          + conv_w[((di * 3 + 2) * 64 + c) * 64 + fch];
  wsB[idx] = f2bf(v * s);
  if (idx < 64) bias[idx] = beta[idx] - mean[idx] * (gamma[idx] * rsqrtf(var[idx] + 1e-3f));
}

// 2048 blocks x 256 threads (32 waves/CU capacity). Each block = half an
// output row; each wave owns ONE 16-px MFMA block. Fully wave-autonomous:
// no __syncthreads; within-wave LDS producer->consumer ordered by lgkmcnt.
__global__ __launch_bounds__(256, 6) void main_kernel(
    const float* __restrict__ fmap, const float* __restrict__ y2,
    const uint4* __restrict__ wsBq, const float* __restrict__ biasg,
    float* __restrict__ out) {
  __shared__ int   s_idx[4][192];
  __shared__ float s_wt[4][192];
  __shared__ uint2 fsA[4][2][64][2];  // [wave][kstep][lpp][h], 8KB

  const int t    = threadIdx.x;
  const int lane = t & 63;
  const int wave = t >> 6;
  // XCD swizzle: pin one batch (fmap_b ~4.2MB ~ one XCD L2) per XCD
  const int b    = blockIdx.x & 7;
  const int rh   = blockIdx.x >> 3;   // 0..255
  const int oi   = rh >> 1;
  const int half = rh & 1;
  const float* fmapb = fmap + (size_t)b * (128 * 128 * 64);
  const int upbase = half * 64 + wave * 16;  // this wave's first pixel

  // ---- Phase 0 (wave-local): coords/weights for this wave's 16 px x 3 di ----
  if (lane < 48) {
    int di  = lane >> 4;
    int upl = lane & 15;
    int up  = upbase + upl;
    int u   = di * 128 + up;
    int j   = u / 3;
    int a   = u - j * 3;
    const float4* yp = reinterpret_cast<const float4*>(
        y2 + ((size_t)(b * 128 + oi) * 128 + j) * 8);
    float4 xv = yp[0];
    float4 yv = yp[1];

    float hi01 = fmaxf(xv.x, xv.y), lo01 = fminf(xv.x, xv.y);
    float hi23 = fmaxf(xv.z, xv.w), lo23 = fminf(xv.z, xv.w);
    float top1 = fmaxf(hi01, hi23);
    float top2 = fmaxf(fminf(hi01, hi23), (hi01 >= hi23) ? lo01 : lo23);
    float w = fminf(fmaxf(top1, 1.f), 127.f) + fminf(fmaxf(top2, 1.f), 127.f);

    hi01 = fmaxf(yv.x, yv.y); lo01 = fminf(yv.x, yv.y);
    hi23 = fmaxf(yv.z, yv.w); lo23 = fminf(yv.z, yv.w);
    top1 = fmaxf(hi01, hi23);
    top2 = fmaxf(fminf(hi01, hi23), (hi01 >= hi23) ? lo01 : lo23);
    float h = fminf(fmaxf(top1, 1.f), 127.f) + fminf(fmaxf(top2, 1.f), 127.f);

    float x, yy;
    if (a == 0)      { x = ((float)j - 1.0f) - w / 3.0f;  yy = ((float)oi - 1.0f) - h / 3.0f; }
    else if (a == 1) { x = (float)j + w * 1e-10f;         yy = (float)oi + h * 1e-10f; }
    else             { x = ((float)j + 1.0f) + w / 3.0f;  yy = ((float)oi + 1.0f) + h / 3.0f; }

    float xl = fminf(fmaxf(floorf(x), 0.f), 127.f);
    float xr = fminf(fmaxf(ceilf(x),  0.f), 127.f);
    float yt = fminf(fmaxf(floorf(yy), 0.f), 127.f);
    float yb = fminf(fmaxf(ceilf(yy),  0.f), 127.f);
    int ixl = (int)xl, ixr = (int)xr, iyt = (int)yt, iyb = (int)yb;
    int lu = di * 64 + wave * 16 + upl;
    s_idx[0][lu] = (iyt * 128 + ixl) * 64;  // lt
    s_idx[1][lu] = (iyt * 128 + ixr) * 64;  // rt
    s_idx[2][lu] = (iyb * 128 + ixl) * 64;  // lb
    s_idx[3][lu] = (iyb * 128 + ixr) * 64;  // rb
    s_wt[0][lu] = xr - x;   // xr_x
    s_wt[1][lu] = x - xl;   // xl_x
    s_wt[2][lu] = yy - yt;  // yt_y
    s_wt[3][lu] = yb - yy;  // yb_y
  }
  __builtin_amdgcn_wave_barrier();

  const int px15 = lane & 15;
  float bias4[4];
  #pragma unroll
  for (int j = 0; j < 4; ++j) bias4[j] = biasg[j * 16 + px15];

  f32x4 acc[4];
  #pragma unroll
  for (int j = 0; j < 4; ++j)
    acc[j] = (f32x4){bias4[j], bias4[j], bias4[j], bias4[j]};

  const int cg  = lane & 15;           // channel quad
  const int g   = cg & 3;
  const int hh  = (cg >> 2) & 1;
  const int ksS = (cg >> 3) & 1;
  const int upg = lane >> 4;           // pixel sub-index per iteration
  const int lsr = lane ^ (2 * (lane >> 4));  // read-side swizzle

  for (int di = 0; di < 3; ++di) {
    // B fragments for this di (L2-resident, 24KB total)
    bf16x8 Bf[8];
    #pragma unroll
    for (int jk = 0; jk < 8; ++jk)
      Bf[jk] = __builtin_bit_cast(bf16x8, wsBq[(di * 8 + jk) * 64 + lane]);

    // ---- Sampling: 16 px x 16 channel-quads = 4 wave-iters ----
    #pragma unroll
    for (int r = 0; r < 4; ++r) {
      int pxi = r * 4 + upg;           // 0..15
      int lu  = di * 64 + wave * 16 + pxi;
      // broadcast LDS reads (16 lanes share the same lu)
      float xr_x = s_wt[0][lu], xl_x = s_wt[1][lu];
      float yt_y = s_wt[2][lu], yb_y = s_wt[3][lu];
      bool need = ((xr_x != 0.f) || (xl_x != 0.f)) &&
                  ((yb_y != 0.f) || (yt_y != 0.f));
      uint2 q = make_uint2(0u, 0u);
      if (need) {
        int c0 = cg * 4;
        int i0 = s_idx[0][lu], i1 = s_idx[1][lu];
        int i2 = s_idx[2][lu], i3 = s_idx[3][lu];
        float4 lt = *reinterpret_cast<const float4*>(fmapb + i0 + c0);
        float4 rt = *reinterpret_cast<const float4*>(fmapb + i1 + c0);
        float4 lb = *reinterpret_cast<const float4*>(fmapb + i2 + c0);
        float4 rb = *reinterpret_cast<const float4*>(fmapb + i3 + c0);
        float v0 = (xr_x * lt.x + xl_x * lb.x) * yb_y + (xr_x * rt.x + xl_x * rb.x) * yt_y;
        float v1 = (xr_x * lt.y + xl_x * lb.y) * yb_y + (xr_x * rt.y + xl_x * rb.y) * yt_y;
        float v2 = (xr_x * lt.z + xl_x * lb.z) * yb_y + (xr_x * rt.z + xl_x * rb.z) * yt_y;
        float v3 = (xr_x * lt.w + xl_x * lb.w) * yb_y + (xr_x * rt.w + xl_x * rb.w) * yt_y;
        q.x = (unsigned)f2bf(v0) | ((unsigned)f2bf(v1) << 16);
        q.y = (unsigned)f2bf(v2) | ((unsigned)f2bf(v3) << 16);
      }
      int lpp = (pxi | (g << 4)) ^ (g << 1);  // bank swizzle
      fsA[wave][ksS][lpp][hh] = q;
    }
    __builtin_amdgcn_wave_barrier();

    // ---- MFMA: wave reads its own slab; 1 pxblk x 4 fch blocks x 2 ksteps ----
    #pragma unroll
    for (int ks = 0; ks < 2; ++ks) {
      bf16x8 a = __builtin_bit_cast(bf16x8,
          *reinterpret_cast<const uint4*>(&fsA[wave][ks][lsr][0]));
      #pragma unroll
      for (int j = 0; j < 4; ++j)
        acc[j] = __builtin_amdgcn_mfma_f32_16x16x32_bf16(a, Bf[j * 2 + ks],
                                                         acc[j], 0, 0, 0);
    }
    __builtin_amdgcn_wave_barrier();
  }

  // ---- Epilogue: ReLU (bias pre-folded); C/D: col=lane&15, row=(lane>>4)*4+reg ----
  float* outb = out + ((size_t)(b * 128 + oi) * 128) * 64;
  const int pxB = upbase + (lane >> 4) * 4;
  #pragma unroll
  for (int j = 0; j < 4; ++j) {
    int fch = j * 16 + px15;
    #pragma unroll
    for (int reg = 0; reg < 4; ++reg) {
      outb[(size_t)(pxB + reg) * 64 + fch] = fmaxf(acc[j][reg], 0.f);
    }
  }
}

extern "C" void kernel_launch(void* const* d_in, const int* in_sizes, int n_in,
                              void* d_out, int out_size, void* d_ws, size_t ws_size,
                              hipStream_t stream) {
  const float* fmap   = (const float*)d_in[0];
  const float* y2     = (const float*)d_in[1];
  const float* conv_w = (const float*)d_in[2];
  const float* gamma  = (const float*)d_in[3];
  const float* beta   = (const float*)d_in[4];
  const float* mean   = (const float*)d_in[5];
  const float* var    = (const float*)d_in[6];
  float* outp = (float*)d_out;

  unsigned short* wsB = (unsigned short*)d_ws;
  float* bias = (float*)((char*)d_ws + 24576);

  prep_kernel<<<48, 256, 0, stream>>>(conv_w, gamma, beta, mean, var, wsB, bias);
  main_kernel<<<2048, 256, 0, stream>>>(fmap, y2, (const uint4*)d_ws, bias, outp);
}

// Round 7
// 46.520 us; speedup vs baseline: 1.0681x; 1.0681x over previous
//
#include <hip/hip_runtime.h>

typedef __bf16 bf16x8 __attribute__((ext_vector_type(8)));
typedef float f32x4 __attribute__((ext_vector_type(4)));

__device__ __forceinline__ unsigned short f2bf(float f) {
  __bf16 h = (__bf16)f;
  return __builtin_bit_cast(unsigned short, h);
}

// d_ws layout: [0, 24576) bytes: wsB bf16 fragment-ordered (12288 shorts)
//              [24576, 24832): bias (64 floats)
// wsB flat idx = (((di*4 + jblk)*2 + kstep)*64 + lane)*8 + i
//   c   = kstep*32 + 4*(lane>>4) + (i&3) + 16*(i>>2)
//   fch = jblk*16 + (lane&15)
__global__ __launch_bounds__(256) void prep_kernel(
    const float* __restrict__ conv_w, const float* __restrict__ gamma,
    const float* __restrict__ beta, const float* __restrict__ mean,
    const float* __restrict__ var, unsigned short* __restrict__ wsB,
    float* __restrict__ bias) {
  int idx = blockIdx.x * 256 + threadIdx.x;
  if (idx >= 12288) return;
  int di    = idx >> 12;
  int r     = idx & 4095;
  int jblk  = r >> 10;
  int r2    = r & 1023;
  int kstep = r2 >> 9;
  int r3    = r2 & 511;
  int lane  = r3 >> 3;
  int i     = r3 & 7;
  int c   = kstep * 32 + 4 * (lane >> 4) + (i & 3) + 16 * (i >> 2);
  int fch = jblk * 16 + (lane & 15);
  float s = gamma[fch] * rsqrtf(var[fch] + 1e-3f);
  float v = conv_w[((di * 3 + 0) * 64 + c) * 64 + fch]
          + conv_w[((di * 3 + 1) * 64 + c) * 64 + fch]
          + conv_w[((di * 3 + 2) * 64 + c) * 64 + fch];
  wsB[idx] = f2bf(v * s);
  if (idx < 64) bias[idx] = beta[idx] - mean[idx] * (gamma[idx] * rsqrtf(var[idx] + 1e-3f));
}

// Wave-autonomous (no __syncthreads), 1024 blocks, 32 px/wave, with an
// explicit 2-slot software pipeline on the corner gathers: slot for step
// m+2 is issued before slot m's MFMA/VALU consumption -> ~8 float4 loads
// in flight per wave. Within-wave LDS producer->consumer ordered by the
// in-order DS pipe; wave_barrier pins code motion.
__global__ __launch_bounds__(256, 4) void main_kernel(
    const float* __restrict__ fmap, const float* __restrict__ y2,
    const uint4* __restrict__ wsBq, const float* __restrict__ biasg,
    float* __restrict__ out) {
  __shared__ int4   s_idx4[384];   // (lt,rt,lb,rb) base offsets
  __shared__ float4 s_wt4[384];    // (xr_x, xl_x, yt_y, yb_y)
  __shared__ uint2  fsA[4][4][64][2];  // [wave][pl*2+kstep][lpp][h], 16KB

  const int t    = threadIdx.x;
  const int lane = t & 63;
  const int wave = t >> 6;
  // XCD swizzle: pin one batch (fmap_b ~4.2MB ~ one XCD L2) per XCD
  const int b  = blockIdx.x & 7;
  const int oi = blockIdx.x >> 3;
  const float* fmapb = fmap + (size_t)b * (128 * 128 * 64);

  // ---- Phase 0 (wave-local): coords/weights for this wave's 32 px x 3 di ----
  #pragma unroll
  for (int it = 0; it < 2; ++it) {
    int e = lane + 64 * it;
    if (e < 96) {
      int di  = e >> 5;
      int upl = e & 31;
      int up  = wave * 32 + upl;
      int u   = di * 128 + up;
      int j   = u / 3;
      int a   = u - j * 3;
      const float4* yp = reinterpret_cast<const float4*>(
          y2 + ((size_t)(b * 128 + oi) * 128 + j) * 8);
      float4 xv = yp[0];
      float4 yv = yp[1];

      float hi01 = fmaxf(xv.x, xv.y), lo01 = fminf(xv.x, xv.y);
      float hi23 = fmaxf(xv.z, xv.w), lo23 = fminf(xv.z, xv.w);
      float top1 = fmaxf(hi01, hi23);
      float top2 = fmaxf(fminf(hi01, hi23), (hi01 >= hi23) ? lo01 : lo23);
      float w = fminf(fmaxf(top1, 1.f), 127.f) + fminf(fmaxf(top2, 1.f), 127.f);

      hi01 = fmaxf(yv.x, yv.y); lo01 = fminf(yv.x, yv.y);
      hi23 = fmaxf(yv.z, yv.w); lo23 = fminf(yv.z, yv.w);
      top1 = fmaxf(hi01, hi23);
      top2 = fmaxf(fminf(hi01, hi23), (hi01 >= hi23) ? lo01 : lo23);
      float h = fminf(fmaxf(top1, 1.f), 127.f) + fminf(fmaxf(top2, 1.f), 127.f);

      float x, yy;
      if (a == 0)      { x = ((float)j - 1.0f) - w / 3.0f;  yy = ((float)oi - 1.0f) - h / 3.0f; }
      else if (a == 1) { x = (float)j + w * 1e-10f;         yy = (float)oi + h * 1e-10f; }
      else             { x = ((float)j + 1.0f) + w / 3.0f;  yy = ((float)oi + 1.0f) + h / 3.0f; }

      float xl = fminf(fmaxf(floorf(x), 0.f), 127.f);
      float xr = fminf(fmaxf(ceilf(x),  0.f), 127.f);
      float yt = fminf(fmaxf(floorf(yy), 0.f), 127.f);
      float yb = fminf(fmaxf(ceilf(yy),  0.f), 127.f);
      int ixl = (int)xl, ixr = (int)xr, iyt = (int)yt, iyb = (int)yb;
      s_idx4[u] = make_int4((iyt * 128 + ixl) * 64, (iyt * 128 + ixr) * 64,
                            (iyb * 128 + ixl) * 64, (iyb * 128 + ixr) * 64);
      s_wt4[u]  = make_float4(xr - x, x - xl, yy - yt, yb - yy);
    }
  }
  __builtin_amdgcn_wave_barrier();

  const int px15 = lane & 15;
  const int cg   = lane & 15;          // channel quad
  const int g    = cg & 3;
  const int hh   = (cg >> 2) & 1;
  const int ksS  = cg >> 3;
  const int upg  = lane >> 4;          // pixel sub-index per iteration
  const int lsr  = lane ^ (2 * (lane >> 4));  // read-side swizzle
  const int c0   = cg * 4;

  f32x4 acc[2][4];
  #pragma unroll
  for (int j = 0; j < 4; ++j) {
    float bv = biasg[j * 16 + px15];
    acc[0][j] = (f32x4){bv, bv, bv, bv};
    acc[1][j] = (f32x4){bv, bv, bv, bv};
  }

  bf16x8 Bf[8];

  float4 lt_A, rt_A, lb_A, rb_A, Wt_A;
  float4 lt_B, rt_B, lb_B, rb_B, Wt_B;
  lt_A = rt_A = lb_A = rb_A = Wt_A = make_float4(0.f, 0.f, 0.f, 0.f);
  lt_B = rt_B = lb_B = rb_B = Wt_B = make_float4(0.f, 0.f, 0.f, 0.f);

#define ISSUE(mm, S) {                                                        \
    const int u_ = ((mm) >> 3) * 128 + wave * 32 + ((mm) & 7) * 4 + upg;      \
    Wt_##S = s_wt4[u_];                                                       \
    bool need_ = ((Wt_##S.x != 0.f) || (Wt_##S.y != 0.f)) &&                  \
                 ((Wt_##S.w != 0.f) || (Wt_##S.z != 0.f));                    \
    if (need_) {                                                              \
      int4 I_ = s_idx4[u_];                                                   \
      lt_##S = *reinterpret_cast<const float4*>(fmapb + I_.x + c0);           \
      rt_##S = *reinterpret_cast<const float4*>(fmapb + I_.y + c0);           \
      lb_##S = *reinterpret_cast<const float4*>(fmapb + I_.z + c0);           \
      rb_##S = *reinterpret_cast<const float4*>(fmapb + I_.w + c0);           \
    }                                                                         \
  }

#define CONSUME(mm, S) {                                                      \
    const int pxi_ = ((mm) & 7) * 4 + upg;                                    \
    bool need_ = ((Wt_##S.x != 0.f) || (Wt_##S.y != 0.f)) &&                  \
                 ((Wt_##S.w != 0.f) || (Wt_##S.z != 0.f));                    \
    uint2 q_ = make_uint2(0u, 0u);                                            \
    if (need_) {                                                              \
      float xr_x = Wt_##S.x, xl_x = Wt_##S.y, yt_y = Wt_##S.z, yb_y = Wt_##S.w; \
      float v0 = (xr_x * lt_##S.x + xl_x * lb_##S.x) * yb_y + (xr_x * rt_##S.x + xl_x * rb_##S.x) * yt_y; \
      float v1 = (xr_x * lt_##S.y + xl_x * lb_##S.y) * yb_y + (xr_x * rt_##S.y + xl_x * rb_##S.y) * yt_y; \
      float v2 = (xr_x * lt_##S.z + xl_x * lb_##S.z) * yb_y + (xr_x * rt_##S.z + xl_x * rb_##S.z) * yt_y; \
      float v3 = (xr_x * lt_##S.w + xl_x * lb_##S.w) * yb_y + (xr_x * rt_##S.w + xl_x * rb_##S.w) * yt_y; \
      q_.x = (unsigned)f2bf(v0) | ((unsigned)f2bf(v1) << 16);                 \
      q_.y = (unsigned)f2bf(v2) | ((unsigned)f2bf(v3) << 16);                 \
    }                                                                         \
    int lpp_ = ((pxi_ & 15) | (g << 4)) ^ (g << 1);                           \
    fsA[wave][(pxi_ >> 4) * 2 + ksS][lpp_][hh] = q_;                          \
  }

  ISSUE(0, A);
  ISSUE(1, B);

  #pragma unroll
  for (int m = 0; m < 24; ++m) {
    if ((m & 7) == 0) {
      const int di_ = m >> 3;
      #pragma unroll
      for (int jk = 0; jk < 8; ++jk)
        Bf[jk] = __builtin_bit_cast(bf16x8, wsBq[(di_ * 8 + jk) * 64 + lane]);
    }
    if ((m & 1) == 0) { CONSUME(m, A); } else { CONSUME(m, B); }
    if (m < 22) {
      if ((m & 1) == 0) { ISSUE(m + 2, A); } else { ISSUE(m + 2, B); }
    }
    if ((m & 7) == 7) {
      __builtin_amdgcn_wave_barrier();
      #pragma unroll
      for (int ks = 0; ks < 2; ++ks) {
        #pragma unroll
        for (int p = 0; p < 2; ++p) {
          bf16x8 a = __builtin_bit_cast(bf16x8,
              *reinterpret_cast<const uint4*>(&fsA[wave][p * 2 + ks][lsr][0]));
          #pragma unroll
          for (int j = 0; j < 4; ++j)
            acc[p][j] = __builtin_amdgcn_mfma_f32_16x16x32_bf16(a, Bf[j * 2 + ks],
                                                                acc[p][j], 0, 0, 0);
        }
      }
      __builtin_amdgcn_wave_barrier();
    }
  }
#undef ISSUE
#undef CONSUME

  // ---- Epilogue: ReLU (bias pre-folded); C/D: col=lane&15, row=(lane>>4)*4+reg ----
  float* outb = out + ((size_t)(b * 128 + oi) * 128) * 64;
  #pragma unroll
  for (int p = 0; p < 2; ++p) {
    int pxB = (wave * 2 + p) * 16 + (lane >> 4) * 4;
    #pragma unroll
    for (int j = 0; j < 4; ++j) {
      int fch = j * 16 + px15;
      #pragma unroll
      for (int reg = 0; reg < 4; ++reg) {
        outb[(size_t)(pxB + reg) * 64 + fch] = fmaxf(acc[p][j][reg], 0.f);
      }
    }
  }
}

extern "C" void kernel_launch(void* const* d_in, const int* in_sizes, int n_in,
                              void* d_out, int out_size, void* d_ws, size_t ws_size,
                              hipStream_t stream) {
  const float* fmap   = (const float*)d_in[0];
  const float* y2     = (const float*)d_in[1];
  const float* conv_w = (const float*)d_in[2];
  const float* gamma  = (const float*)d_in[3];
  const float* beta   = (const float*)d_in[4];
  const float* mean   = (const float*)d_in[5];
  const float* var    = (const float*)d_in[6];
  float* outp = (float*)d_out;

  unsigned short* wsB = (unsigned short*)d_ws;
  float* bias = (float*)((char*)d_ws + 24576);

  prep_kernel<<<48, 256, 0, stream>>>(conv_w, gamma, beta, mean, var, wsB, bias);
  main_kernel<<<1024, 256, 0, stream>>>(fmap, y2, (const uint4*)d_ws, bias, outp);
}

// Round 8
// 39.617 us; speedup vs baseline: 1.2542x; 1.1742x over previous
//
#include <hip/hip_runtime.h>

typedef __bf16 bf16x8 __attribute__((ext_vector_type(8)));
typedef float f32x4 __attribute__((ext_vector_type(4)));

__device__ __forceinline__ unsigned short f2bf(float f) {
  __bf16 h = (__bf16)f;
  return __builtin_bit_cast(unsigned short, h);
}

// d_ws layout: [0, 24576) bytes: wsB bf16 fragment-ordered (12288 shorts)
//              [24576, 24832): bias (64 floats)
// wsB flat idx = (((di*4 + jblk)*2 + kstep)*64 + lane)*8 + i
//   c   = kstep*32 + 4*(lane>>4) + (i&3) + 16*(i>>2)
//   fch = jblk*16 + (lane&15)
__global__ __launch_bounds__(256) void prep_kernel(
    const float* __restrict__ conv_w, const float* __restrict__ gamma,
    const float* __restrict__ beta, const float* __restrict__ mean,
    const float* __restrict__ var, unsigned short* __restrict__ wsB,
    float* __restrict__ bias) {
  int idx = blockIdx.x * 256 + threadIdx.x;
  if (idx >= 12288) return;
  int di    = idx >> 12;
  int r     = idx & 4095;
  int jblk  = r >> 10;
  int r2    = r & 1023;
  int kstep = r2 >> 9;
  int r3    = r2 & 511;
  int lane  = r3 >> 3;
  int i     = r3 & 7;
  int c   = kstep * 32 + 4 * (lane >> 4) + (i & 3) + 16 * (i >> 2);
  int fch = jblk * 16 + (lane & 15);
  float s = gamma[fch] * rsqrtf(var[fch] + 1e-3f);
  float v = conv_w[((di * 3 + 0) * 64 + c) * 64 + fch]
          + conv_w[((di * 3 + 1) * 64 + c) * 64 + fch]
          + conv_w[((di * 3 + 2) * 64 + c) * 64 + fch];
  wsB[idx] = f2bf(v * s);
  if (idx < 64) bias[idx] = beta[idx] - mean[idx] * (gamma[idx] * rsqrtf(var[idx] + 1e-3f));
}

// 2048 blocks x 256 threads: half an output row per block, one 16-px MFMA
// block per wave. Wave-autonomous (no __syncthreads). Explicit 2-slot
// software pipeline over 12 gather steps (3 di x 4 iters): slot m+2 issued
// before slot m is consumed -> up to 8 float4 gathers in flight per wave.
// No launch-bounds reg cap: live state ~90 VGPR, must not spill
// (canary: WRITE_SIZE ~= 34 MB).
__global__ __launch_bounds__(256) void main_kernel(
    const float* __restrict__ fmap, const float* __restrict__ y2,
    const uint4* __restrict__ wsBq, const float* __restrict__ biasg,
    float* __restrict__ out) {
  __shared__ int4   s_idx4[192];   // (lt,rt,lb,rb) base offsets
  __shared__ float4 s_wt4[192];    // (xr_x, xl_x, yt_y, yb_y)
  __shared__ uint2  fsA[4][2][64][2];  // [wave][kstep][lpp][h], 8KB

  const int t    = threadIdx.x;
  const int lane = t & 63;
  const int wave = t >> 6;
  // XCD swizzle: pin one batch (fmap_b ~4.2MB ~ one XCD L2) per XCD
  const int b    = blockIdx.x & 7;
  const int rh   = blockIdx.x >> 3;   // 0..255
  const int oi   = rh >> 1;
  const int half = rh & 1;
  const float* fmapb = fmap + (size_t)b * (128 * 128 * 64);
  const int upbase = half * 64 + wave * 16;  // this wave's first pixel

  // ---- Phase 0 (wave-local): coords/weights for this wave's 16 px x 3 di ----
  if (lane < 48) {
    int di  = lane >> 4;
    int upl = lane & 15;
    int up  = upbase + upl;
    int u   = di * 128 + up;
    int j   = u / 3;
    int a   = u - j * 3;
    const float4* yp = reinterpret_cast<const float4*>(
        y2 + ((size_t)(b * 128 + oi) * 128 + j) * 8);
    float4 xv = yp[0];
    float4 yv = yp[1];

    float hi01 = fmaxf(xv.x, xv.y), lo01 = fminf(xv.x, xv.y);
    float hi23 = fmaxf(xv.z, xv.w), lo23 = fminf(xv.z, xv.w);
    float top1 = fmaxf(hi01, hi23);
    float top2 = fmaxf(fminf(hi01, hi23), (hi01 >= hi23) ? lo01 : lo23);
    float w = fminf(fmaxf(top1, 1.f), 127.f) + fminf(fmaxf(top2, 1.f), 127.f);

    hi01 = fmaxf(yv.x, yv.y); lo01 = fminf(yv.x, yv.y);
    hi23 = fmaxf(yv.z, yv.w); lo23 = fminf(yv.z, yv.w);
    top1 = fmaxf(hi01, hi23);
    top2 = fmaxf(fminf(hi01, hi23), (hi01 >= hi23) ? lo01 : lo23);
    float h = fminf(fmaxf(top1, 1.f), 127.f) + fminf(fmaxf(top2, 1.f), 127.f);

    float x, yy;
    if (a == 0)      { x = ((float)j - 1.0f) - w / 3.0f;  yy = ((float)oi - 1.0f) - h / 3.0f; }
    else if (a == 1) { x = (float)j + w * 1e-10f;         yy = (float)oi + h * 1e-10f; }
    else             { x = ((float)j + 1.0f) + w / 3.0f;  yy = ((float)oi + 1.0f) + h / 3.0f; }

    float xl = fminf(fmaxf(floorf(x), 0.f), 127.f);
    float xr = fminf(fmaxf(ceilf(x),  0.f), 127.f);
    float yt = fminf(fmaxf(floorf(yy), 0.f), 127.f);
    float yb = fminf(fmaxf(ceilf(yy),  0.f), 127.f);
    int ixl = (int)xl, ixr = (int)xr, iyt = (int)yt, iyb = (int)yb;
    int lu = di * 64 + wave * 16 + upl;
    s_idx4[lu] = make_int4((iyt * 128 + ixl) * 64, (iyt * 128 + ixr) * 64,
                           (iyb * 128 + ixl) * 64, (iyb * 128 + ixr) * 64);
    s_wt4[lu]  = make_float4(xr - x, x - xl, yy - yt, yb - yy);
  }
  __builtin_amdgcn_wave_barrier();

  const int px15 = lane & 15;
  const int cg   = lane & 15;          // channel quad
  const int g    = cg & 3;
  const int hh   = (cg >> 2) & 1;
  const int ksS  = (cg >> 3) & 1;
  const int upg  = lane >> 4;          // pixel sub-index per iteration
  const int lsr  = lane ^ (2 * (lane >> 4));  // read-side swizzle
  const int c0   = cg * 4;

  f32x4 acc[4];
  #pragma unroll
  for (int j = 0; j < 4; ++j) {
    float bv = biasg[j * 16 + px15];
    acc[j] = (f32x4){bv, bv, bv, bv};
  }

  float4 lt_A, rt_A, lb_A, rb_A, Wt_A;
  float4 lt_B, rt_B, lb_B, rb_B, Wt_B;
  lt_A = rt_A = lb_A = rb_A = Wt_A = make_float4(0.f, 0.f, 0.f, 0.f);
  lt_B = rt_B = lb_B = rb_B = Wt_B = make_float4(0.f, 0.f, 0.f, 0.f);

  // step m (0..11): di = m>>2, pxi = (m&3)*4 + upg
#define ISSUE(mm, S) {                                                        \
    const int lu_ = ((mm) >> 2) * 64 + wave * 16 + ((mm) & 3) * 4 + upg;      \
    Wt_##S = s_wt4[lu_];                                                      \
    bool need_ = ((Wt_##S.x != 0.f) || (Wt_##S.y != 0.f)) &&                  \
                 ((Wt_##S.w != 0.f) || (Wt_##S.z != 0.f));                    \
    if (need_) {                                                              \
      int4 I_ = s_idx4[lu_];                                                  \
      lt_##S = *reinterpret_cast<const float4*>(fmapb + I_.x + c0);           \
      rt_##S = *reinterpret_cast<const float4*>(fmapb + I_.y + c0);           \
      lb_##S = *reinterpret_cast<const float4*>(fmapb + I_.z + c0);           \
      rb_##S = *reinterpret_cast<const float4*>(fmapb + I_.w + c0);           \
    }                                                                         \
  }

#define CONSUME(mm, S) {                                                      \
    const int pxi_ = ((mm) & 3) * 4 + upg;                                    \
    bool need_ = ((Wt_##S.x != 0.f) || (Wt_##S.y != 0.f)) &&                  \
                 ((Wt_##S.w != 0.f) || (Wt_##S.z != 0.f));                    \
    uint2 q_ = make_uint2(0u, 0u);                                            \
    if (need_) {                                                              \
      float xr_x = Wt_##S.x, xl_x = Wt_##S.y, yt_y = Wt_##S.z, yb_y = Wt_##S.w; \
      float v0 = (xr_x * lt_##S.x + xl_x * lb_##S.x) * yb_y + (xr_x * rt_##S.x + xl_x * rb_##S.x) * yt_y; \
      float v1 = (xr_x * lt_##S.y + xl_x * lb_##S.y) * yb_y + (xr_x * rt_##S.y + xl_x * rb_##S.y) * yt_y; \
      float v2 = (xr_x * lt_##S.z + xl_x * lb_##S.z) * yb_y + (xr_x * rt_##S.z + xl_x * rb_##S.z) * yt_y; \
      float v3 = (xr_x * lt_##S.w + xl_x * lb_##S.w) * yb_y + (xr_x * rt_##S.w + xl_x * rb_##S.w) * yt_y; \
      q_.x = (unsigned)f2bf(v0) | ((unsigned)f2bf(v1) << 16);                 \
      q_.y = (unsigned)f2bf(v2) | ((unsigned)f2bf(v3) << 16);                 \
    }                                                                         \
    int lpp_ = (pxi_ | (g << 4)) ^ (g << 1);                                  \
    fsA[wave][ksS][lpp_][hh] = q_;                                            \
  }

  ISSUE(0, A);
  ISSUE(1, B);

  #pragma unroll
  for (int m = 0; m < 12; ++m) {
    if ((m & 1) == 0) { CONSUME(m, A); } else { CONSUME(m, B); }
    if (m < 10) {
      if ((m & 1) == 0) { ISSUE(m + 2, A); } else { ISSUE(m + 2, B); }
    }
    if ((m & 3) == 3) {
      const int di_ = m >> 2;
      __builtin_amdgcn_wave_barrier();
      #pragma unroll
      for (int ks = 0; ks < 2; ++ks) {
        bf16x8 Bf4[4];
        #pragma unroll
        for (int j = 0; j < 4; ++j)
          Bf4[j] = __builtin_bit_cast(bf16x8, wsBq[(di_ * 8 + j * 2 + ks) * 64 + lane]);
        bf16x8 a = __builtin_bit_cast(bf16x8,
            *reinterpret_cast<const uint4*>(&fsA[wave][ks][lsr][0]));
        #pragma unroll
        for (int j = 0; j < 4; ++j)
          acc[j] = __builtin_amdgcn_mfma_f32_16x16x32_bf16(a, Bf4[j], acc[j], 0, 0, 0);
      }
      __builtin_amdgcn_wave_barrier();
    }
  }
#undef ISSUE
#undef CONSUME

  // ---- Epilogue: ReLU (bias pre-folded); C/D: col=lane&15, row=(lane>>4)*4+reg ----
  float* outb = out + ((size_t)(b * 128 + oi) * 128) * 64;
  const int pxB = upbase + (lane >> 4) * 4;
  #pragma unroll
  for (int j = 0; j < 4; ++j) {
    int fch = j * 16 + px15;
    #pragma unroll
    for (int reg = 0; reg < 4; ++reg) {
      outb[(size_t)(pxB + reg) * 64 + fch] = fmaxf(acc[j][reg], 0.f);
    }
  }
}

extern "C" void kernel_launch(void* const* d_in, const int* in_sizes, int n_in,
                              void* d_out, int out_size, void* d_ws, size_t ws_size,
                              hipStream_t stream) {
  const float* fmap   = (const float*)d_in[0];
  const float* y2     = (const float*)d_in[1];
  const float* conv_w = (const float*)d_in[2];
  const float* gamma  = (const float*)d_in[3];
  const float* beta   = (const float*)d_in[4];
  const float* mean   = (const float*)d_in[5];
  const float* var    = (const float*)d_in[6];
  float* outp = (float*)d_out;

  unsigned short* wsB = (unsigned short*)d_ws;
  float* bias = (float*)((char*)d_ws + 24576);

  prep_kernel<<<48, 256, 0, stream>>>(conv_w, gamma, beta, mean, var, wsB, bias);
  main_kernel<<<2048, 256, 0, stream>>>(fmap, y2, (const uint4*)d_ws, bias, outp);
}